// Round 2
// baseline (24.882 us; speedup 1.0000x reference)
//
#include <hip/hip_runtime.h>

#define BATCH 512
#define NNEG  2048
#define DIM   128
#define PADR  132   // padded LDS row stride (floats): bank group 4*(l+j)%32, 8 words/bank = floor

typedef int s16x __attribute__((ext_vector_type(16)));

// 32-float (128 B) scalar chunk load: 2x s_load_dwordx16
#define SLOAD2(r0, r1, p) \
  asm volatile("s_load_dwordx16 %0, %2, 0x0\n\t" \
               "s_load_dwordx16 %1, %2, 0x40" \
               : "=s"(r0), "=s"(r1) : "s"(p))

// lgkmcnt(0) with def of the tuples so consumers can't be hoisted above it
#define SWAIT2(r0, r1) \
  asm volatile("s_waitcnt lgkmcnt(0)" : "+s"(r0), "+s"(r1))

__device__ __forceinline__ void chunk32(const s16x& a0, const s16x& a1,
                                        const float4* tr,
                                        float& sx, float& sy, float& sz, float& sw) {
#pragma unroll
  for (int u = 0; u < 4; ++u) {
    float4 t = tr[u];
    sx += fabsf(__int_as_float(a0[4*u+0]) - t.x);
    sy += fabsf(__int_as_float(a0[4*u+1]) - t.y);
    sz += fabsf(__int_as_float(a0[4*u+2]) - t.z);
    sw += fabsf(__int_as_float(a0[4*u+3]) - t.w);
  }
#pragma unroll
  for (int u = 0; u < 4; ++u) {
    float4 t = tr[u+4];
    sx += fabsf(__int_as_float(a1[4*u+0]) - t.x);
    sy += fabsf(__int_as_float(a1[4*u+1]) - t.y);
    sz += fabsf(__int_as_float(a1[4*u+2]) - t.z);
    sw += fabsf(__int_as_float(a1[4*u+3]) - t.w);
  }
}

// q[b] = head[b] + relemb[relid[b]]  (512x128 floats into d_ws)
__global__ __launch_bounds__(256)
void compute_q(const float* __restrict__ head, const int* __restrict__ relid,
               const float* __restrict__ relemb, float* __restrict__ q) {
  int i  = blockIdx.x * 256 + threadIdx.x;   // 16384 threads, float4 each
  int b  = i >> 5, c4 = i & 31;
  int rid = relid[b];
  float4 h = *reinterpret_cast<const float4*>(&head[b * DIM + c4 * 4]);
  float4 r = *reinterpret_cast<const float4*>(&relemb[rid * DIM + c4 * 4]);
  float4 o;
  o.x = h.x + r.x; o.y = h.y + r.y; o.z = h.z + r.z; o.w = h.w + r.w;
  *reinterpret_cast<float4*>(&q[b * DIM + c4 * 4]) = o;
}

// Main: block = 4 waves sharing 64 tails (lane = tail, row in regs);
// each wave handles 8 batch rows, query streamed through SGPRs.
__global__ __launch_bounds__(256, 2)
void transe_main(const float* __restrict__ tail, const float* __restrict__ q,
                 float* __restrict__ out) {
  __shared__ float lt[64 * PADR];   // 33,792 B

  const int tid = threadIdx.x;
  const int bx  = blockIdx.x;
  const int tt  = bx & 31;          // 32 tail tiles
  const int bg  = bx >> 5;          // 16 batch groups
  const int t0  = tt * 64;
  const int b0  = bg * 32;

  // ---- stage 64 tail rows, coalesced ----
#pragma unroll
  for (int m = 0; m < 8; ++m) {
    int k = tid + m * 256;
    int row = k >> 5, c4 = k & 31;
    float4 v = *reinterpret_cast<const float4*>(&tail[(t0 + row) * DIM + c4 * 4]);
    *reinterpret_cast<float4*>(&lt[row * PADR + c4 * 4]) = v;
  }
  __syncthreads();

  const int lane = tid & 63;
  const int wq   = __builtin_amdgcn_readfirstlane(tid >> 6);  // wave id, SGPR
  const float* qb = q + (b0 + wq * 8) * DIM;

  s16x A0, A1, B0, B1;
  SLOAD2(A0, A1, qb);               // row0 chunk0 in flight during tr fill

  // ---- own tail row -> 128 VGPRs (one-time; 8 words/bank = conflict floor) ----
  float4 tr[32];
#pragma unroll
  for (int j = 0; j < 32; ++j)
    tr[j] = *reinterpret_cast<const float4*>(&lt[lane * PADR + j * 4]);

  SWAIT2(A0, A1);                   // drains the ds_reads too

  float res[8];
  float sx, sy, sz, sw;

  // flat chunk stream c = 0..31 (8 rows x 4 chunks of 32 floats),
  // issue next chunk -> compute current -> wait(0): latency hides under compute
#define STEP(C0, C1, N0, N1, c)                                         \
  do {                                                                  \
    if ((c) < 31) { SLOAD2(N0, N1, qb + ((c) + 1) * 32); }              \
    const int rr_ = (c) >> 2, s4_ = (c) & 3;                            \
    if (s4_ == 0) { sx = sy = sz = sw = 0.f; }                          \
    chunk32(C0, C1, &tr[8 * s4_], sx, sy, sz, sw);                      \
    if (s4_ == 3) res[rr_] = -((sx + sy) + (sz + sw));                  \
    if ((c) < 31) { SWAIT2(N0, N1); }                                   \
  } while (0)

  STEP(A0,A1,B0,B1, 0); STEP(B0,B1,A0,A1, 1); STEP(A0,A1,B0,B1, 2); STEP(B0,B1,A0,A1, 3);
  STEP(A0,A1,B0,B1, 4); STEP(B0,B1,A0,A1, 5); STEP(A0,A1,B0,B1, 6); STEP(B0,B1,A0,A1, 7);
  STEP(A0,A1,B0,B1, 8); STEP(B0,B1,A0,A1, 9); STEP(A0,A1,B0,B1,10); STEP(B0,B1,A0,A1,11);
  STEP(A0,A1,B0,B1,12); STEP(B0,B1,A0,A1,13); STEP(A0,A1,B0,B1,14); STEP(B0,B1,A0,A1,15);
  STEP(A0,A1,B0,B1,16); STEP(B0,B1,A0,A1,17); STEP(A0,A1,B0,B1,18); STEP(B0,B1,A0,A1,19);
  STEP(A0,A1,B0,B1,20); STEP(B0,B1,A0,A1,21); STEP(A0,A1,B0,B1,22); STEP(B0,B1,A0,A1,23);
  STEP(A0,A1,B0,B1,24); STEP(B0,B1,A0,A1,25); STEP(A0,A1,B0,B1,26); STEP(B0,B1,A0,A1,27);
  STEP(A0,A1,B0,B1,28); STEP(B0,B1,A0,A1,29); STEP(A0,A1,B0,B1,30); STEP(B0,B1,A0,A1,31);
#undef STEP

  const int brow = b0 + wq * 8;
#pragma unroll
  for (int r = 0; r < 8; ++r)
    out[(size_t)(brow + r) * NNEG + t0 + lane] = res[r];
}

// ---------------- fallback (round-1 kernel) if d_ws is too small ----------------
__global__ __launch_bounds__(256)
void transe_l1_fallback(const float* __restrict__ head, const int* __restrict__ relid,
                        const float* __restrict__ tail, const float* __restrict__ relemb,
                        float* __restrict__ out) {
  __shared__ float ltail[64 * PADR];
  __shared__ float lq[32 * PADR];
  const int tid = threadIdx.x, bx = blockIdx.x;
  const int t0 = (bx & 31) * 64, b0 = (bx >> 5) * 32;
#pragma unroll
  for (int m = 0; m < 4; ++m) {
    int k = tid + m * 256, row = k >> 5, c4 = k & 31, b = b0 + row;
    int rid = relid[b];
    float4 h = *reinterpret_cast<const float4*>(&head[b * DIM + c4 * 4]);
    float4 r = *reinterpret_cast<const float4*>(&relemb[rid * DIM + c4 * 4]);
    float4 qv; qv.x=h.x+r.x; qv.y=h.y+r.y; qv.z=h.z+r.z; qv.w=h.w+r.w;
    *reinterpret_cast<float4*>(&lq[row * PADR + c4 * 4]) = qv;
  }
#pragma unroll
  for (int m = 0; m < 8; ++m) {
    int k = tid + m * 256, row = k >> 5, c4 = k & 31;
    float4 tv = *reinterpret_cast<const float4*>(&tail[(t0 + row) * DIM + c4 * 4]);
    *reinterpret_cast<float4*>(&ltail[row * PADR + c4 * 4]) = tv;
  }
  __syncthreads();
  const int ts = tid & 7, bs = tid >> 3;
  float4 qv[32];
#pragma unroll
  for (int j = 0; j < 32; ++j)
    qv[j] = *reinterpret_cast<const float4*>(&lq[bs * PADR + j * 4]);
  float res[8];
#pragma unroll
  for (int i = 0; i < 8; ++i) {
    const float* trp = &ltail[(i * 8 + ts) * PADR];
    float sx = 0.f, sy = 0.f, sz = 0.f, sw = 0.f;
#pragma unroll
    for (int j = 0; j < 32; ++j) {
      float4 tv = *reinterpret_cast<const float4*>(&trp[j * 4]);
      sx += fabsf(qv[j].x - tv.x); sy += fabsf(qv[j].y - tv.y);
      sz += fabsf(qv[j].z - tv.z); sw += fabsf(qv[j].w - tv.w);
    }
    res[i] = -((sx + sy) + (sz + sw));
  }
  const int b = b0 + bs;
#pragma unroll
  for (int i = 0; i < 8; ++i)
    out[b * NNEG + t0 + i * 8 + ts] = res[i];
}

extern "C" void kernel_launch(void* const* d_in, const int* in_sizes, int n_in,
                              void* d_out, int out_size, void* d_ws, size_t ws_size,
                              hipStream_t stream) {
  const float* head   = (const float*)d_in[0];
  const int*   relid  = (const int*)d_in[1];
  const float* tail   = (const float*)d_in[2];
  const float* relemb = (const float*)d_in[3];
  float*       out    = (float*)d_out;

  const size_t q_bytes = (size_t)BATCH * DIM * sizeof(float);
  if (ws_size >= q_bytes) {
    float* q = (float*)d_ws;
    compute_q<<<dim3(BATCH * DIM / 4 / 256), dim3(256), 0, stream>>>(head, relid, relemb, q);
    transe_main<<<dim3(32 * 16), dim3(256), 0, stream>>>(tail, q, out);
  } else {
    transe_l1_fallback<<<dim3(512), dim3(256), 0, stream>>>(head, relid, tail, relemb, out);
  }
}

// Round 3
// 15.046 us; speedup vs baseline: 1.6537x; 1.6537x over previous
//
#include <hip/hip_runtime.h>

#define BATCH 512
#define NNEG  2048
#define DIM   128

// Block: 256 threads (4 waves). Tile: 32 q-rows x 64 tails.
// Wave w: q-rows [b0+8w, b0+8w+8), all 64 tails.
// Lane (dg,tg), dg=lane>>3, tg=lane&7:
//   holds tails {8k+tg, k=0..7} x dims [16*dg, 16*dg+16) in 128 VGPRs,
//   per q-row reads its private 64B of q (4x ds_read_b128, 8-lane broadcast,
//   bank groups 4*dg -> conflict-free), accumulates 8 rows x 8 tails partials,
//   then routed shfl_xor tree (masks 8/16/32) leaves row=dg results in-lane.
// LDS layouts:
//   tails: granule (r,g) at word r*128 + 4*(g ^ (r&7))   (XOR swizzle; read rows
//          8k+tg have r&7 = tg -> 64 distinct granules spread over all banks)
//   q:     granule (r,g) at word r*128 + 4*((g>>2) + (g&3)*8)  (dg-major so the
//          8 dg-granules per read land on 8 distinct bank groups)

__global__ __launch_bounds__(256, 2)
void transe_l1(const float* __restrict__ head,
               const int*   __restrict__ relid,
               const float* __restrict__ tailp,
               const float* __restrict__ relemb,
               float* __restrict__ out) {
  __shared__ float lds[96 * 128];            // 48 KB
  float* lt = lds;                            // tails: 64 rows * 128 words
  float* lq = lds + 64 * 128;                 // q:     32 rows * 128 words

  const int tid = threadIdx.x;
  const int bx  = blockIdx.x;
  const int t0  = (bx & 31) * 64;             // 32 tail tiles
  const int b0  = (bx >> 5) * 32;             // 16 batch groups

  // ---- stage tails (coalesced global read, swizzled LDS write) ----
#pragma unroll
  for (int m = 0; m < 8; ++m) {
    int k = tid + m * 256;                    // 0..2047
    int r = k >> 5, g = k & 31;
    float4 v = *reinterpret_cast<const float4*>(&tailp[(t0 + r) * DIM + g * 4]);
    int p = g ^ (r & 7);
    *reinterpret_cast<float4*>(&lt[r * 128 + p * 4]) = v;
  }
  // ---- stage q = head + relemb[relid] (fused, permuted LDS write) ----
#pragma unroll
  for (int m = 0; m < 4; ++m) {
    int k = tid + m * 256;                    // 0..1023
    int r = k >> 5, g = k & 31;
    int b = b0 + r;
    int rid = relid[b];
    float4 h = *reinterpret_cast<const float4*>(&head[b * DIM + g * 4]);
    float4 e = *reinterpret_cast<const float4*>(&relemb[rid * DIM + g * 4]);
    float4 v;
    v.x = h.x + e.x; v.y = h.y + e.y; v.z = h.z + e.z; v.w = h.w + e.w;
    int p = (g >> 2) + (g & 3) * 8;
    *reinterpret_cast<float4*>(&lq[r * 128 + p * 4]) = v;
  }
  __syncthreads();

  const int lane = tid & 63;
  const int w    = tid >> 6;
  const int tg   = lane & 7;
  const int dg   = lane >> 3;

  // ---- tail fragment -> 128 VGPRs: tf[k][j] = tails[8k+tg][16*dg + 4j ..] ----
  float4 tf[8][4];
#pragma unroll
  for (int k = 0; k < 8; ++k) {
#pragma unroll
    for (int j = 0; j < 4; ++j) {
      int p = (dg * 4 + j) ^ tg;
      tf[k][j] = *reinterpret_cast<const float4*>(&lt[(8 * k + tg) * 128 + p * 4]);
    }
  }

  float acc[8][8];                            // [row][k] partials (16 dims each)
#pragma unroll
  for (int r = 0; r < 8; ++r)
#pragma unroll
    for (int k = 0; k < 8; ++k) acc[r][k] = 0.f;

  const int qbase = (w * 8) * 128;
#pragma unroll
  for (int r = 0; r < 8; ++r) {
    float4 qf[4];
#pragma unroll
    for (int j = 0; j < 4; ++j)
      qf[j] = *reinterpret_cast<const float4*>(&lq[qbase + r * 128 + (dg + 8 * j) * 4]);
#pragma unroll
    for (int k = 0; k < 8; ++k) {
#pragma unroll
      for (int j = 0; j < 4; ++j) {
        acc[r][k] += fabsf(qf[j].x - tf[k][j].x);
        acc[r][k] += fabsf(qf[j].y - tf[k][j].y);
        acc[r][k] += fabsf(qf[j].z - tf[k][j].z);
        acc[r][k] += fabsf(qf[j].w - tf[k][j].w);
      }
    }
  }

  // ---- routed reduction across dg: lane ends with row = dg (static indices) ----
  const int brow = b0 + w * 8 + dg;
#pragma unroll
  for (int k = 0; k < 8; ++k) {
    float s4[4];
#pragma unroll
    for (int i = 0; i < 4; ++i) {
      float a  = acc[2 * i][k], b = acc[2 * i + 1][k];
      float xa = __shfl_xor(a, 8), xb = __shfl_xor(b, 8);
      s4[i] = (dg & 1) ? (b + xb) : (a + xa);       // keep rows with r0 == dg0
    }
    float s2[2];
#pragma unroll
    for (int i = 0; i < 2; ++i) {
      float a  = s4[2 * i], b = s4[2 * i + 1];
      float xa = __shfl_xor(a, 16), xb = __shfl_xor(b, 16);
      s2[i] = (dg & 2) ? (b + xb) : (a + xa);       // keep rows with r1 == dg1
    }
    float a  = s2[0], b = s2[1];
    float xa = __shfl_xor(a, 32), xb = __shfl_xor(b, 32);
    float v  = (dg & 4) ? (b + xb) : (a + xa);      // row r2 == dg2 -> row = dg
    out[brow * NNEG + t0 + 8 * k + tg] = -v;
  }
}

extern "C" void kernel_launch(void* const* d_in, const int* in_sizes, int n_in,
                              void* d_out, int out_size, void* d_ws, size_t ws_size,
                              hipStream_t stream) {
  const float* head   = (const float*)d_in[0];
  const int*   relid  = (const int*)d_in[1];
  const float* tailp  = (const float*)d_in[2];
  const float* relemb = (const float*)d_in[3];
  float*       out    = (float*)d_out;

  transe_l1<<<dim3(512), dim3(256), 0, stream>>>(head, relid, tailp, relemb, out);
}